// Round 6
// baseline (541.455 us; speedup 1.0000x reference)
//
#include <hip/hip_runtime.h>
#include <math.h>

#define VOCAB 1024
#define ED 64
#define NROWS 65536            // 64*32*32 flattened rows
#define NELEM 4194304          // 64*64*32*32
#define MARGIN 2.0e-4f         // validated R3/R4/R5 (passed, absmax 0)
#define CAPN 4096              // candidate-rescue slots (expect ~2600 flagged)
#define CAPFULL 16384          // full-rescue slots (expect ~50; also CAPN overflow)

typedef __attribute__((ext_vector_type(8))) short short8;
typedef __attribute__((ext_vector_type(4))) float f32x4;

__device__ __forceinline__ unsigned f2bf(float f) {
    unsigned u = __float_as_uint(f);
    u += 0x7fff + ((u >> 16) & 1);   // RNE to bf16
    return u >> 16;
}

// ws layout:
//   [0,      4096)   float  e2f[1024]        fl32(fp64 ||e||^2)  (R2-proven)
//   [4096,   135168) ushort Bf[...]          bf16 codebook, MFMA-B fragment order
//   [135168, 135176) double loss_sum
//   [135176, 135180) unsigned nflagN
//   [135180, 135184) unsigned nflagF
//   [135184, 139280) unsigned hist[1024]
//   [139280, 204816) unsigned listF[CAPFULL]
//   [204816, 221200) unsigned listN[CAPN]
//   [221200, 286736) uint4    candN[CAPN]    8 candidate codes (2 per uint)

// ---------------- prep: e2f + fragment-ordered bf16 codebook ----------------
__global__ void vq_prep(const float* __restrict__ emb, float* __restrict__ e2f,
                        unsigned short* __restrict__ Bf) {
    int v = blockIdx.x * 256 + threadIdx.x;
    if (v >= VOCAB) return;
    float vals[ED];
    const float4* src = (const float4*)(emb + v * ED);
    double s = 0.0;
    #pragma unroll
    for (int g = 0; g < 16; ++g) {
        float4 f = src[g];
        vals[4*g] = f.x; vals[4*g+1] = f.y; vals[4*g+2] = f.z; vals[4*g+3] = f.w;
        s = fma((double)f.x, (double)f.x, s);
        s = fma((double)f.y, (double)f.y, s);
        s = fma((double)f.z, (double)f.z, s);
        s = fma((double)f.w, (double)f.w, s);
    }
    e2f[v] = (float)s;
    // B-fragment order: lane L = q*16+n holds B[n][k=kh*32+q*8+j], tile = v>>4
    const int tile = v >> 4, n = v & 15;
    #pragma unroll
    for (int k8 = 0; k8 < 8; ++k8) {
        const int kh = k8 >> 2, q = k8 & 3, L = q * 16 + n;
        uint4 pk;
        pk.x = f2bf(vals[k8*8+0]) | (f2bf(vals[k8*8+1]) << 16);
        pk.y = f2bf(vals[k8*8+2]) | (f2bf(vals[k8*8+3]) << 16);
        pk.z = f2bf(vals[k8*8+4]) | (f2bf(vals[k8*8+5]) << 16);
        pk.w = f2bf(vals[k8*8+6]) | (f2bf(vals[k8*8+7]) << 16);
        ((uint4*)Bf)[(tile * 2 + kh) * 64 + L] = pk;
    }
}

// ---------------- filter: barrier-free MFMA scan, top-3/wave, no phase 2 -----
__global__ __launch_bounds__(256, 3)
void vq_filter(const float* __restrict__ z, const float* __restrict__ emb,
               const float* __restrict__ e2f, const unsigned short* __restrict__ Bf,
               float* __restrict__ out, double* __restrict__ loss_sum,
               unsigned* __restrict__ hist, unsigned* __restrict__ nflagN,
               unsigned* __restrict__ nflagF, unsigned* __restrict__ listF,
               unsigned* __restrict__ listN, uint4* __restrict__ candN) {
    __shared__ float zs[64 * 67];      // fp32 z rows [row][k], pad 67 (2-way free)
    __shared__ uint4 afr[512];         // bf16(-2z) A-fragments [rt][kh][lane]
    __shared__ float Mb1[256], Mb2[256], Mb3[256];
    __shared__ int   Mi1[256], Mi2[256];
    __shared__ int   final_code[64], final_flag[64];

    const int t = threadIdx.x;
    const int w = t >> 6, lane = t & 63;
    const int q = lane >> 4, n_lo = lane & 15;
    const int bk = blockIdx.x;         // 1024 blocks, 64 rows each
    const int n0 = bk * 64;
    const int b  = n0 >> 10;
    const int sbase = n0 & 1023;

    // ---- stage z rows (coalesced 256B per instr) ----
    {
        const int row = t & 63, dg = t >> 6;
        #pragma unroll
        for (int i = 0; i < 16; ++i) {
            int d = dg * 16 + i;
            zs[row * 67 + d] = z[(size_t)b * 65536 + (size_t)d * 1024 + sbase + row];
        }
    }
    __syncthreads();

    // ---- build A-fragments once per block (bf16(-2z), validated numerics) ----
    for (int e = t; e < 512; e += 256) {
        const int rt = e >> 7, kh = (e >> 6) & 1, L = e & 63;
        const int qq = L >> 4, nn = L & 15;
        const int row = rt * 16 + nn, k0 = kh * 32 + qq * 8;
        uint4 pk;
        pk.x = f2bf(-2.0f * zs[row*67 + k0+0]) | (f2bf(-2.0f * zs[row*67 + k0+1]) << 16);
        pk.y = f2bf(-2.0f * zs[row*67 + k0+2]) | (f2bf(-2.0f * zs[row*67 + k0+3]) << 16);
        pk.z = f2bf(-2.0f * zs[row*67 + k0+4]) | (f2bf(-2.0f * zs[row*67 + k0+5]) << 16);
        pk.w = f2bf(-2.0f * zs[row*67 + k0+6]) | (f2bf(-2.0f * zs[row*67 + k0+7]) << 16);
        afr[e] = pk;
    }
    __syncthreads();

    // A-frags to registers (stride-1 b128 LDS reads)
    short8 af[4][2];
    #pragma unroll
    for (int rt = 0; rt < 4; ++rt)
        #pragma unroll
        for (int kh = 0; kh < 2; ++kh)
            af[rt][kh] = ((const short8*)afr)[(rt * 2 + kh) * 64 + lane];

    // per-slot top-3 (values) + top-2 indices. slot -> row = rt*16 + q*4 + reg
    float b1[16], b2[16], b3[16]; int i1[16], i2[16];
    #pragma unroll
    for (int sl = 0; sl < 16; ++sl) {
        b1[sl] = 3.4e38f; b2[sl] = 3.4e38f; b3[sl] = 3.4e38f;
        i1[sl] = 0; i2[sl] = 0;
    }

    // ---- scan: wave w owns codes [w*256, w*256+256), B-frags from global/L2 ----
    const short8* Bq = (const short8*)Bf + (size_t)(w * 16) * 128;  // 16 tiles x 2 kh x 64
    #pragma unroll 4
    for (int lt = 0; lt < 16; ++lt) {
        short8 bf0 = Bq[(lt * 2 + 0) * 64 + lane];
        short8 bf1 = Bq[(lt * 2 + 1) * 64 + lane];
        const int codec = w * 256 + lt * 16 + n_lo;
        const float e2c = e2f[codec];
        #pragma unroll
        for (int rt = 0; rt < 4; ++rt) {
            f32x4 a; a[0] = e2c; a[1] = e2c; a[2] = e2c; a[3] = e2c;
            a = __builtin_amdgcn_mfma_f32_16x16x32_bf16(af[rt][0], bf0, a, 0, 0, 0);
            a = __builtin_amdgcn_mfma_f32_16x16x32_bf16(af[rt][1], bf1, a, 0, 0, 0);
            #pragma unroll
            for (int reg = 0; reg < 4; ++reg) {
                const int sl = rt * 4 + reg;
                const float s = a[reg];
                const bool lt1 = s < b1[sl];
                const bool lt2 = s < b2[sl];
                b3[sl] = __builtin_amdgcn_fmed3f(s, b2[sl], b3[sl]);
                i2[sl] = lt1 ? i1[sl] : (lt2 ? codec : i2[sl]);
                b2[sl] = __builtin_amdgcn_fmed3f(s, b1[sl], b2[sl]);
                i1[sl] = lt1 ? codec : i1[sl];
                b1[sl] = fminf(s, b1[sl]);
            }
        }
    }

    // ---- quad butterfly merge (16 code-lanes), exact top-3 values + top-2 idx ----
    #pragma unroll
    for (int m = 1; m < 16; m <<= 1) {
        #pragma unroll
        for (int sl = 0; sl < 16; ++sl) {
            float ob1 = __shfl_xor(b1[sl], m, 64);
            int   oi1 = __shfl_xor(i1[sl], m, 64);
            float ob2 = __shfl_xor(b2[sl], m, 64);
            int   oi2 = __shfl_xor(i2[sl], m, 64);
            float ob3 = __shfl_xor(b3[sl], m, 64);
            // merged 3rd value: med3(max(a1,c1), min(a2,c2), min(a3,c3))
            float m3 = __builtin_amdgcn_fmed3f(fmaxf(b1[sl], ob1),
                                               fminf(b2[sl], ob2),
                                               fminf(b3[sl], ob3));
            bool t1 = (ob1 < b1[sl]) || (ob1 == b1[sl] && oi1 < i1[sl]);
            float x1 = t1 ? ob1 : b1[sl];  int xi1 = t1 ? oi1 : i1[sl];
            float ra = t1 ? b1[sl] : ob1;  int rai = t1 ? i1[sl] : oi1;  // loser of 1st
            float rb = t1 ? ob2 : b2[sl];  int rbi = t1 ? oi2 : i2[sl];  // winner-side 2nd
            bool t2 = (rb < ra) || (rb == ra && rbi < rai);
            b2[sl] = t2 ? rb : ra;  i2[sl] = t2 ? rbi : rai;
            b1[sl] = x1;  i1[sl] = xi1;  b3[sl] = m3;
        }
    }
    if (n_lo == 0) {
        #pragma unroll
        for (int rt = 0; rt < 4; ++rt) {
            #pragma unroll
            for (int reg = 0; reg < 4; ++reg) {
                const int row = rt * 16 + q * 4 + reg;
                const int sl = rt * 4 + reg;
                Mb1[w * 64 + row] = b1[sl];  Mi1[w * 64 + row] = i1[sl];
                Mb2[w * 64 + row] = b2[sl];  Mi2[w * 64 + row] = i2[sl];
                Mb3[w * 64 + row] = b3[sl];
            }
        }
    }
    __syncthreads();

    // ---- cross-wave merge + routing (one thread per row) ----
    if (t < 64) {
        float B1 = Mb1[t]; int I1 = Mi1[t]; float B2 = Mb2[t];
        float b3min = Mb3[t];
        #pragma unroll
        for (int ww = 1; ww < 4; ++ww) {
            float v1 = Mb1[ww*64 + t]; int j1 = Mi1[ww*64 + t];
            float v2 = Mb2[ww*64 + t]; int j2 = Mi2[ww*64 + t];
            b3min = fminf(b3min, Mb3[ww*64 + t]);
            bool lt1 = (v1 < B1) || (v1 == B1 && j1 < I1);
            B2 = lt1 ? B1 : fminf(v1, B2);
            if (lt1) { B1 = v1; I1 = j1; }
            bool lt2 = (v2 < B1) || (v2 == B1 && j2 < I1);
            B2 = lt2 ? B1 : fminf(v2, B2);
            if (lt2) { B1 = v2; I1 = j2; }
        }
        const bool full = b3min < B1 + MARGIN;
        const bool flagged = (B2 < B1 + MARGIN) || full;
        const int nrow = n0 + t;
        out[NELEM + nrow] = (float)I1;          // rescue overwrites if flagged
        final_code[t] = I1;
        final_flag[t] = flagged ? 1 : 0;
        if (!flagged) {
            atomicAdd(&hist[I1], 1u);
        } else if (full) {
            unsigned p = atomicAdd(nflagF, 1u);
            if (p < CAPFULL) listF[p] = (unsigned)nrow;
        } else {
            unsigned p = atomicAdd(nflagN, 1u);
            if (p < CAPN) {
                listN[p] = (unsigned)nrow;
                uint4 c8;
                c8.x = (unsigned)Mi1[t]       | ((unsigned)Mi2[t]       << 16);
                c8.y = (unsigned)Mi1[64 + t]  | ((unsigned)Mi2[64 + t]  << 16);
                c8.z = (unsigned)Mi1[128 + t] | ((unsigned)Mi2[128 + t] << 16);
                c8.w = (unsigned)Mi1[192 + t] | ((unsigned)Mi2[192 + t] << 16);
                candN[p] = c8;
            } else {
                unsigned p2 = atomicAdd(nflagF, 1u);
                if (p2 < CAPFULL) listF[p2] = (unsigned)nrow;
            }
        }
    }
    __syncthreads();

    // ---- epilogue: coalesced z_q_st + loss (lane owns row, w owns d-quarter) ----
    {
        const int row = lane;
        const int code = final_code[row];
        const bool fl = final_flag[row] != 0;
        double lsum = 0.0;
        #pragma unroll
        for (int i = 0; i < 16; ++i) {
            const int d = w * 16 + i;
            float zv = zs[row * 67 + d];
            float ee = emb[code * 64 + d];          // divergent, L1/L2-hot
            size_t off = (size_t)b * 65536 + (size_t)d * 1024 + sbase + row;
            out[off] = zv + (ee - zv);              // coalesced 256B
            double df = (double)ee - (double)zv;
            lsum = fma(df, df, lsum);
        }
        if (fl) lsum = 0.0;                         // rescue adds flagged rows
        #pragma unroll
        for (int off = 32; off > 0; off >>= 1)
            lsum += __shfl_down(lsum, off, 64);
        if (lane == 0) atomicAdd(loss_sum, lsum);
    }
}

// ---------------- rescue: wave-per-row full scan + thread-per-row candidates --
__global__ __launch_bounds__(256, 1)
void vq_rescue(const float* __restrict__ z, const float* __restrict__ emb,
               const float* __restrict__ e2f, float* __restrict__ out,
               double* __restrict__ loss_sum, unsigned* __restrict__ hist,
               const unsigned* __restrict__ nflagN, const unsigned* __restrict__ nflagF,
               const unsigned* __restrict__ listF, const unsigned* __restrict__ listN,
               const uint4* __restrict__ candN) {
    const int t = threadIdx.x, w = t >> 6, lane = t & 63;
    unsigned nFr = *nflagF, nNr = *nflagN;
    const int nF = (int)(nFr < CAPFULL ? nFr : CAPFULL);
    const int nN = (int)(nNr < CAPN ? nNr : CAPN);

    // ---- part A: wave-per-row FULL exact scan (rare) ----
    for (int fi = blockIdx.x * 4 + w; fi < nF; fi += gridDim.x * 4) {
        const int row = (int)listF[fi];
        const int b = row >> 10, s = row & 1023;
        float zr[64];
        #pragma unroll
        for (int k = 0; k < 64; ++k)
            zr[k] = z[(size_t)b * 65536 + (size_t)k * 1024 + s];  // wave-uniform
        double a = 0.0;
        #pragma unroll
        for (int k = 0; k < 64; ++k) a = fma((double)zr[k], (double)zr[k], a);
        const float zn = (float)a;
        float bv = 3.4e38f; int bi = 0x7fffffff;
        #pragma unroll 1
        for (int g = 0; g < 16; ++g) {
            const int c = lane * 16 + g;              // lane-local ascending
            float m = 0.f;
            const float4* ep = (const float4*)(emb + c * 64);
            #pragma unroll
            for (int k4 = 0; k4 < 16; ++k4) {         // R2-exact sequential k
                float4 e4 = ep[k4];
                m = fmaf(zr[4*k4+0], e4.x, m); m = fmaf(zr[4*k4+1], e4.y, m);
                m = fmaf(zr[4*k4+2], e4.z, m); m = fmaf(zr[4*k4+3], e4.w, m);
            }
            float tt = zn + e2f[c];
            float d = tt - 2.0f * m;
            if (d < bv) { bv = d; bi = c; }
        }
        #pragma unroll
        for (int mm = 1; mm < 64; mm <<= 1) {
            float od = __shfl_xor(bv, mm, 64);
            int   oc = __shfl_xor(bi, mm, 64);
            if (od < bv || (od == bv && oc < bi)) { bv = od; bi = oc; }
        }
        float ee = emb[bi * 64 + lane];
        float zv = z[(size_t)b * 65536 + (size_t)lane * 1024 + s];
        out[(size_t)b * 65536 + (size_t)lane * 1024 + s] = zv + (ee - zv);
        double df = (double)ee - (double)zv;
        double ls = df * df;
        #pragma unroll
        for (int off = 32; off > 0; off >>= 1) ls += __shfl_xor(ls, off, 64);
        if (lane == 0) {
            out[NELEM + row] = (float)bi;
            atomicAdd(&hist[bi], 1u);
            atomicAdd(loss_sum, ls);
        }
    }

    // ---- part B: thread-per-row over 8 candidates (R5-proven path) ----
    for (int i = blockIdx.x * 256 + t; i < nN; i += gridDim.x * 256) {
        const int row = (int)listN[i];
        const int b = row >> 10, s = row & 1023;
        uint4 c8 = candN[i];
        int cand[8];
        cand[0] = (int)(c8.x & 0xFFFFu); cand[1] = (int)(c8.x >> 16);
        cand[2] = (int)(c8.y & 0xFFFFu); cand[3] = (int)(c8.y >> 16);
        cand[4] = (int)(c8.z & 0xFFFFu); cand[5] = (int)(c8.z >> 16);
        cand[6] = (int)(c8.w & 0xFFFFu); cand[7] = (int)(c8.w >> 16);
        float zr[64];
        #pragma unroll
        for (int k = 0; k < 64; ++k)
            zr[k] = z[(size_t)b * 65536 + (size_t)k * 1024 + s];
        double a = 0.0;
        #pragma unroll
        for (int k = 0; k < 64; ++k) a = fma((double)zr[k], (double)zr[k], a);
        const float zn = (float)a;
        float bv = 3.4e38f; int bi = 0x7fffffff;
        #pragma unroll
        for (int j = 0; j < 8; ++j) {
            const int c = cand[j];
            float m = 0.f;
            const float4* ep = (const float4*)(emb + c * 64);
            #pragma unroll
            for (int k4 = 0; k4 < 16; ++k4) {         // R2-exact sequential k
                float4 e4 = ep[k4];
                m = fmaf(zr[4*k4+0], e4.x, m); m = fmaf(zr[4*k4+1], e4.y, m);
                m = fmaf(zr[4*k4+2], e4.z, m); m = fmaf(zr[4*k4+3], e4.w, m);
            }
            float tt = zn + e2f[c];
            float d = tt - 2.0f * m;
            if (d < bv || (d == bv && c < bi)) { bv = d; bi = c; }
        }
        out[NELEM + row] = (float)bi;
        atomicAdd(&hist[bi], 1u);
        double lsum = 0.0;
        #pragma unroll
        for (int k = 0; k < 64; ++k) {
            float e = emb[bi * 64 + k];
            size_t off = (size_t)b * 65536 + (size_t)k * 1024 + s;
            out[off] = zr[k] + (e - zr[k]);
            double df = (double)e - (double)zr[k];
            lsum = fma(df, df, lsum);
        }
        atomicAdd(loss_sum, lsum);
    }
}

// ---------------- finalize ----------------
__global__ void vq_finalize_kernel(const unsigned* __restrict__ hist,
                                   const double* __restrict__ loss_sum,
                                   float* __restrict__ out) {
    __shared__ double red[256];
    int t = threadIdx.x;
    double ssum = 0.0;
    for (int i = t; i < VOCAB; i += 256) {
        double p = (double)hist[i] / (double)NROWS;
        ssum += p * log(p + 1e-10);
    }
    red[t] = ssum;
    __syncthreads();
    for (int off = 128; off > 0; off >>= 1) {
        if (t < off) red[t] += red[t + off];
        __syncthreads();
    }
    if (t == 0) {
        double qv = loss_sum[0] / (double)NELEM;
        out[NELEM + NROWS + 0] = (float)qv;
        out[NELEM + NROWS + 1] = (float)(qv * 0.25);
        out[NELEM + NROWS + 2] = (float)exp(-red[0]);
    }
}

extern "C" void kernel_launch(void* const* d_in, const int* in_sizes, int n_in,
                              void* d_out, int out_size, void* d_ws, size_t ws_size,
                              hipStream_t stream) {
    const float* z   = (const float*)d_in[0];   // (64,64,32,32) fp32
    const float* emb = (const float*)d_in[1];   // (1024,64) fp32
    float* out = (float*)d_out;

    float*          e2f   = (float*)d_ws;
    unsigned short* Bf    = (unsigned short*)((char*)d_ws + 4096);
    double*         loss  = (double*)((char*)d_ws + 135168);
    unsigned*       nflN  = (unsigned*)((char*)d_ws + 135176);
    unsigned*       nflF  = (unsigned*)((char*)d_ws + 135180);
    unsigned*       hist  = (unsigned*)((char*)d_ws + 135184);
    unsigned*       listF = (unsigned*)((char*)d_ws + 139280);
    unsigned*       listN = (unsigned*)((char*)d_ws + 204816);
    uint4*          candN = (uint4*)((char*)d_ws + 221200);

    // zero loss + nflagN + nflagF + hist
    hipMemsetAsync((char*)d_ws + 135168, 0, 4112, stream);

    vq_prep<<<dim3(4), dim3(256), 0, stream>>>(emb, e2f, Bf);
    vq_filter<<<dim3(1024), dim3(256), 0, stream>>>(z, emb, e2f, Bf, out, loss,
                                                    hist, nflN, nflF, listF,
                                                    listN, candN);
    vq_rescue<<<dim3(64), dim3(256), 0, stream>>>(z, emb, e2f, out, loss, hist,
                                                  nflN, nflF, listF, listN, candN);
    vq_finalize_kernel<<<dim3(1), dim3(256), 0, stream>>>(hist, loss, out);
}

// Round 7
// 374.410 us; speedup vs baseline: 1.4462x; 1.4462x over previous
//
#include <hip/hip_runtime.h>
#include <math.h>

#define VOCAB 1024
#define ED 64
#define NROWS 65536            // 64*32*32 flattened rows
#define NELEM 4194304          // 64*64*32*32
#define MARGIN 2.0e-4f         // validated R3/R4/R5 (passed, absmax 0)
#define CAPFULL 65536          // full-rescue slots (expect ~2600 flagged)

typedef __attribute__((ext_vector_type(8))) short short8;
typedef __attribute__((ext_vector_type(4))) float f32x4;

__device__ __forceinline__ unsigned f2bf(float f) {
    unsigned u = __float_as_uint(f);
    u += 0x7fff + ((u >> 16) & 1);   // RNE to bf16
    return u >> 16;
}

// ws layout:
//   [0,      4096)   float  e2f[1024]        fl32(fp64 ||e||^2)  (R2-proven)
//   [4096,   135168) ushort Bf[...]          bf16 codebook, MFMA-B fragment order
//   [135168, 135176) double loss_sum
//   [135176, 135180) unsigned nflagF
//   [135180, 135184) pad
//   [135184, 139280) unsigned hist[1024]
//   [139280, 401424) unsigned listF[CAPFULL]

// ---------------- prep: e2f + fragment-ordered bf16 codebook ----------------
__global__ void vq_prep(const float* __restrict__ emb, float* __restrict__ e2f,
                        unsigned short* __restrict__ Bf) {
    int v = blockIdx.x * 256 + threadIdx.x;
    if (v >= VOCAB) return;
    float vals[ED];
    const float4* src = (const float4*)(emb + v * ED);
    double s = 0.0;
    #pragma unroll
    for (int g = 0; g < 16; ++g) {
        float4 f = src[g];
        vals[4*g] = f.x; vals[4*g+1] = f.y; vals[4*g+2] = f.z; vals[4*g+3] = f.w;
        s = fma((double)f.x, (double)f.x, s);
        s = fma((double)f.y, (double)f.y, s);
        s = fma((double)f.z, (double)f.z, s);
        s = fma((double)f.w, (double)f.w, s);
    }
    e2f[v] = (float)s;
    // B-fragment order: lane L = q*16+n holds B[n][k=kh*32+q*8+j], tile = v>>4
    const int tile = v >> 4, n = v & 15;
    #pragma unroll
    for (int k8 = 0; k8 < 8; ++k8) {
        const int kh = k8 >> 2, q = k8 & 3, L = q * 16 + n;
        uint4 pk;
        pk.x = f2bf(vals[k8*8+0]) | (f2bf(vals[k8*8+1]) << 16);
        pk.y = f2bf(vals[k8*8+2]) | (f2bf(vals[k8*8+3]) << 16);
        pk.z = f2bf(vals[k8*8+4]) | (f2bf(vals[k8*8+5]) << 16);
        pk.w = f2bf(vals[k8*8+6]) | (f2bf(vals[k8*8+7]) << 16);
        ((uint4*)Bf)[(tile * 2 + kh) * 64 + L] = pk;
    }
}

// ---------------- filter: barrier-free MFMA scan, top-2 per row --------------
__global__ __launch_bounds__(256, 2)
void vq_filter(const float* __restrict__ z, const float* __restrict__ emb,
               const float* __restrict__ e2f, const unsigned short* __restrict__ Bf,
               float* __restrict__ out, double* __restrict__ loss_sum,
               unsigned* __restrict__ hist, unsigned* __restrict__ nflagF,
               unsigned* __restrict__ listF) {
    __shared__ float zs[64 * 67];      // fp32 z rows [row][k], pad 67
    __shared__ uint4 afr[512];         // bf16(-2z) A-fragments [rt][kh][lane]
    __shared__ float Mb1[256], Mb2[256];
    __shared__ int   Mi1[256];
    __shared__ int   final_code[64], final_flag[64];

    const int t = threadIdx.x;
    const int w = t >> 6, lane = t & 63;
    const int q = lane >> 4, n_lo = lane & 15;
    const int bk = blockIdx.x;         // 1024 blocks, 64 rows each
    const int n0 = bk * 64;
    const int b  = n0 >> 10;
    const int sbase = n0 & 1023;

    // ---- stage z rows (coalesced 256B per instr) ----
    {
        const int row = t & 63, dg = t >> 6;
        #pragma unroll
        for (int i = 0; i < 16; ++i) {
            int d = dg * 16 + i;
            zs[row * 67 + d] = z[(size_t)b * 65536 + (size_t)d * 1024 + sbase + row];
        }
    }
    __syncthreads();

    // ---- build A-fragments once per block (bf16(-2z), validated numerics) ----
    for (int e = t; e < 512; e += 256) {
        const int rt = e >> 7, kh = (e >> 6) & 1, L = e & 63;
        const int qq = L >> 4, nn = L & 15;
        const int row = rt * 16 + nn, k0 = kh * 32 + qq * 8;
        uint4 pk;
        pk.x = f2bf(-2.0f * zs[row*67 + k0+0]) | (f2bf(-2.0f * zs[row*67 + k0+1]) << 16);
        pk.y = f2bf(-2.0f * zs[row*67 + k0+2]) | (f2bf(-2.0f * zs[row*67 + k0+3]) << 16);
        pk.z = f2bf(-2.0f * zs[row*67 + k0+4]) | (f2bf(-2.0f * zs[row*67 + k0+5]) << 16);
        pk.w = f2bf(-2.0f * zs[row*67 + k0+6]) | (f2bf(-2.0f * zs[row*67 + k0+7]) << 16);
        afr[e] = pk;
    }
    __syncthreads();

    // A-frags to registers (stride-1 b128 LDS reads, conflict-free)
    short8 af[4][2];
    #pragma unroll
    for (int rt = 0; rt < 4; ++rt)
        #pragma unroll
        for (int kh = 0; kh < 2; ++kh)
            af[rt][kh] = ((const short8*)afr)[(rt * 2 + kh) * 64 + lane];

    // per-slot top-2 values + top-1 index. slot -> row = rt*16 + q*4 + reg
    float b1[16], b2[16]; int i1[16];
    #pragma unroll
    for (int sl = 0; sl < 16; ++sl) { b1[sl] = 3.4e38f; b2[sl] = 3.4e38f; i1[sl] = 0; }

    // ---- scan: wave w owns codes [w*256, w*256+256), B-frags from global/L2 ----
    const short8* Bq = (const short8*)Bf + (size_t)(w * 16) * 128;
    #pragma unroll 2
    for (int lt = 0; lt < 16; ++lt) {
        short8 bf0 = Bq[(lt * 2 + 0) * 64 + lane];
        short8 bf1 = Bq[(lt * 2 + 1) * 64 + lane];
        const int codec = w * 256 + lt * 16 + n_lo;
        const float e2c = e2f[codec];
        #pragma unroll
        for (int rt = 0; rt < 4; ++rt) {
            f32x4 a; a[0] = e2c; a[1] = e2c; a[2] = e2c; a[3] = e2c;
            a = __builtin_amdgcn_mfma_f32_16x16x32_bf16(af[rt][0], bf0, a, 0, 0, 0);
            a = __builtin_amdgcn_mfma_f32_16x16x32_bf16(af[rt][1], bf1, a, 0, 0, 0);
            #pragma unroll
            for (int reg = 0; reg < 4; ++reg) {
                const int sl = rt * 4 + reg;
                const float s = a[reg];
                b2[sl] = __builtin_amdgcn_fmed3f(s, b1[sl], b2[sl]);
                const bool lt1 = s < b1[sl];
                i1[sl] = lt1 ? codec : i1[sl];
                b1[sl] = fminf(s, b1[sl]);
            }
        }
    }

    // ---- quad butterfly merge (16 code-lanes): exact top-2 + index ----
    #pragma unroll
    for (int m = 1; m < 16; m <<= 1) {
        #pragma unroll
        for (int sl = 0; sl < 16; ++sl) {
            float ob1 = __shfl_xor(b1[sl], m, 64);
            int   oi1 = __shfl_xor(i1[sl], m, 64);
            float ob2 = __shfl_xor(b2[sl], m, 64);
            float lose = fmaxf(b1[sl], ob1);
            b2[sl] = fminf(fminf(b2[sl], ob2), lose);
            bool take = (ob1 < b1[sl]) || (ob1 == b1[sl] && oi1 < i1[sl]);
            b1[sl] = take ? ob1 : b1[sl];
            i1[sl] = take ? oi1 : i1[sl];
        }
    }
    if (n_lo == 0) {
        #pragma unroll
        for (int rt = 0; rt < 4; ++rt) {
            #pragma unroll
            for (int reg = 0; reg < 4; ++reg) {
                const int row = rt * 16 + q * 4 + reg;
                const int sl = rt * 4 + reg;
                Mb1[w * 64 + row] = b1[sl];
                Mb2[w * 64 + row] = b2[sl];
                Mi1[w * 64 + row] = i1[sl];
            }
        }
    }
    __syncthreads();

    // ---- cross-wave merge + routing (one thread per row) ----
    if (t < 64) {
        float B1 = Mb1[t]; int I1 = Mi1[t]; float B2 = Mb2[t];
        #pragma unroll
        for (int ww = 1; ww < 4; ++ww) {
            float v1 = Mb1[ww*64 + t]; int j1 = Mi1[ww*64 + t];
            float v2 = Mb2[ww*64 + t];
            if (v1 < B1 || (v1 == B1 && j1 < I1)) {
                B2 = fminf(B1, v2);
                B1 = v1; I1 = j1;
            } else {
                B2 = fminf(B2, v1);
            }
        }
        const bool flagged = B2 < B1 + MARGIN;
        const int nrow = n0 + t;
        out[NELEM + nrow] = (float)I1;          // rescue overwrites if flagged
        final_code[t] = I1;
        final_flag[t] = flagged ? 1 : 0;
        if (!flagged) {
            atomicAdd(&hist[I1], 1u);
        } else {
            unsigned p = atomicAdd(nflagF, 1u);
            if (p < CAPFULL) listF[p] = (unsigned)nrow;
        }
    }
    __syncthreads();

    // ---- epilogue: coalesced z_q_st + loss (lane owns row, w owns d-quarter) ----
    {
        const int row = lane;
        const int code = final_code[row];
        const bool fl = final_flag[row] != 0;
        double lsum = 0.0;
        #pragma unroll
        for (int i = 0; i < 16; ++i) {
            const int d = w * 16 + i;
            float zv = zs[row * 67 + d];
            float ee = emb[code * 64 + d];          // divergent gather, L1/L2-hot
            size_t off = (size_t)b * 65536 + (size_t)d * 1024 + sbase + row;
            out[off] = zv + (ee - zv);              // coalesced 256B
            double df = (double)ee - (double)zv;
            lsum = fma(df, df, lsum);
        }
        if (fl) lsum = 0.0;                         // rescue adds flagged rows
        #pragma unroll
        for (int off = 32; off > 0; off >>= 1)
            lsum += __shfl_down(lsum, off, 64);
        if (lane == 0) atomicAdd(loss_sum, lsum);
    }
}

// ---------------- rescue: wave-per-row FULL exact scan (R2-proven chain) -----
__global__ __launch_bounds__(256)
void vq_rescue(const float* __restrict__ z, const float* __restrict__ emb,
               const float* __restrict__ e2f, float* __restrict__ out,
               double* __restrict__ loss_sum, unsigned* __restrict__ hist,
               const unsigned* __restrict__ nflagF,
               const unsigned* __restrict__ listF) {
    const int t = threadIdx.x, w = t >> 6, lane = t & 63;
    unsigned nFr = *nflagF;
    const int nF = (int)(nFr < CAPFULL ? nFr : CAPFULL);

    for (int fi = blockIdx.x * 4 + w; fi < nF; fi += gridDim.x * 4) {
        const int row = (int)listF[fi];
        const int b = row >> 10, s = row & 1023;
        float zr[64];
        #pragma unroll
        for (int k = 0; k < 64; ++k)
            zr[k] = z[(size_t)b * 65536 + (size_t)k * 1024 + s];  // wave-uniform
        double a = 0.0;
        #pragma unroll
        for (int k = 0; k < 64; ++k) a = fma((double)zr[k], (double)zr[k], a);
        const float zn = (float)a;        // fl32(fp64 ||z||^2), R2-proven
        float bv = 3.4e38f; int bi = 0x7fffffff;
        // lane owns codes [lane*16, lane*16+16); 4 independent chains x 4 groups
        #pragma unroll 1
        for (int g = 0; g < 4; ++g) {
            const int c0 = lane * 16 + g * 4;
            const float4* p0 = (const float4*)(emb + (c0 + 0) * 64);
            const float4* p1 = (const float4*)(emb + (c0 + 1) * 64);
            const float4* p2 = (const float4*)(emb + (c0 + 2) * 64);
            const float4* p3 = (const float4*)(emb + (c0 + 3) * 64);
            float m0 = 0.f, m1 = 0.f, m2 = 0.f, m3 = 0.f;
            #pragma unroll
            for (int k4 = 0; k4 < 16; ++k4) {         // R2-exact sequential k
                float4 e0 = p0[k4], e1 = p1[k4], e2_ = p2[k4], e3 = p3[k4];
                m0 = fmaf(zr[4*k4+0], e0.x, m0);  m0 = fmaf(zr[4*k4+1], e0.y, m0);
                m0 = fmaf(zr[4*k4+2], e0.z, m0);  m0 = fmaf(zr[4*k4+3], e0.w, m0);
                m1 = fmaf(zr[4*k4+0], e1.x, m1);  m1 = fmaf(zr[4*k4+1], e1.y, m1);
                m1 = fmaf(zr[4*k4+2], e1.z, m1);  m1 = fmaf(zr[4*k4+3], e1.w, m1);
                m2 = fmaf(zr[4*k4+0], e2_.x, m2); m2 = fmaf(zr[4*k4+1], e2_.y, m2);
                m2 = fmaf(zr[4*k4+2], e2_.z, m2); m2 = fmaf(zr[4*k4+3], e2_.w, m2);
                m3 = fmaf(zr[4*k4+0], e3.x, m3);  m3 = fmaf(zr[4*k4+1], e3.y, m3);
                m3 = fmaf(zr[4*k4+2], e3.z, m3);  m3 = fmaf(zr[4*k4+3], e3.w, m3);
            }
            float tt, d;
            tt = zn + e2f[c0+0]; d = tt - 2.0f*m0; if (d < bv) { bv = d; bi = c0+0; }
            tt = zn + e2f[c0+1]; d = tt - 2.0f*m1; if (d < bv) { bv = d; bi = c0+1; }
            tt = zn + e2f[c0+2]; d = tt - 2.0f*m2; if (d < bv) { bv = d; bi = c0+2; }
            tt = zn + e2f[c0+3]; d = tt - 2.0f*m3; if (d < bv) { bv = d; bi = c0+3; }
        }
        #pragma unroll
        for (int mm = 1; mm < 64; mm <<= 1) {
            float od = __shfl_xor(bv, mm, 64);
            int   oc = __shfl_xor(bi, mm, 64);
            if (od < bv || (od == bv && oc < bi)) { bv = od; bi = oc; }
        }
        float ee = emb[bi * 64 + lane];
        float zv = zr[lane];
        out[(size_t)b * 65536 + (size_t)lane * 1024 + s] = zv + (ee - zv);
        double df = (double)ee - (double)zv;
        double ls = df * df;
        #pragma unroll
        for (int off = 32; off > 0; off >>= 1) ls += __shfl_xor(ls, off, 64);
        if (lane == 0) {
            out[NELEM + row] = (float)bi;
            atomicAdd(&hist[bi], 1u);
            atomicAdd(loss_sum, ls);
        }
    }
}

// ---------------- finalize ----------------
__global__ void vq_finalize_kernel(const unsigned* __restrict__ hist,
                                   const double* __restrict__ loss_sum,
                                   float* __restrict__ out) {
    __shared__ double red[256];
    int t = threadIdx.x;
    double ssum = 0.0;
    for (int i = t; i < VOCAB; i += 256) {
        double p = (double)hist[i] / (double)NROWS;
        ssum += p * log(p + 1e-10);
    }
    red[t] = ssum;
    __syncthreads();
    for (int off = 128; off > 0; off >>= 1) {
        if (t < off) red[t] += red[t + off];
        __syncthreads();
    }
    if (t == 0) {
        double qv = loss_sum[0] / (double)NELEM;
        out[NELEM + NROWS + 0] = (float)qv;
        out[NELEM + NROWS + 1] = (float)(qv * 0.25);
        out[NELEM + NROWS + 2] = (float)exp(-red[0]);
    }
}

extern "C" void kernel_launch(void* const* d_in, const int* in_sizes, int n_in,
                              void* d_out, int out_size, void* d_ws, size_t ws_size,
                              hipStream_t stream) {
    const float* z   = (const float*)d_in[0];   // (64,64,32,32) fp32
    const float* emb = (const float*)d_in[1];   // (1024,64) fp32
    float* out = (float*)d_out;

    float*          e2f   = (float*)d_ws;
    unsigned short* Bf    = (unsigned short*)((char*)d_ws + 4096);
    double*         loss  = (double*)((char*)d_ws + 135168);
    unsigned*       nflF  = (unsigned*)((char*)d_ws + 135176);
    unsigned*       hist  = (unsigned*)((char*)d_ws + 135184);
    unsigned*       listF = (unsigned*)((char*)d_ws + 139280);

    // zero loss + nflagF + pad + hist
    hipMemsetAsync((char*)d_ws + 135168, 0, 4112, stream);

    vq_prep<<<dim3(4), dim3(256), 0, stream>>>(emb, e2f, Bf);
    vq_filter<<<dim3(1024), dim3(256), 0, stream>>>(z, emb, e2f, Bf, out, loss,
                                                    hist, nflF, listF);
    vq_rescue<<<dim3(512), dim3(256), 0, stream>>>(z, emb, e2f, out, loss, hist,
                                                   nflF, listF);
    vq_finalize_kernel<<<dim3(1), dim3(256), 0, stream>>>(hist, loss, out);
}

// Round 8
// 333.293 us; speedup vs baseline: 1.6246x; 1.1234x over previous
//
#include <hip/hip_runtime.h>
#include <math.h>

#define VOCAB 1024
#define ED 64
#define NROWS 65536            // 64*32*32 flattened rows
#define NELEM 4194304          // 64*64*32*32
#define MARGIN 2.0e-4f         // validated R3/R4/R5/R7 (passed, absmax 0)
#define CAPFULL 65536          // = NROWS, cannot overflow

typedef __attribute__((ext_vector_type(8))) short short8;
typedef __attribute__((ext_vector_type(4))) float f32x4;

__device__ __forceinline__ unsigned f2bf(float f) {
    unsigned u = __float_as_uint(f);
    u += 0x7fff + ((u >> 16) & 1);   // RNE to bf16
    return u >> 16;
}

// ws layout:
//   [0,      4096)   float  e2f[1024]        fl32(fp64 ||e||^2)  (R2-proven)
//   [4096,   135168) ushort Bf[...]          bf16 codebook, MFMA-B fragment order
//   [135168, 135176) double loss_sum
//   [135176, 135180) unsigned nflagF
//   [135180, 135184) pad
//   [135184, 139280) unsigned hist[1024]
//   [139280, 401424) unsigned listF[CAPFULL]

// ---------------- prep: e2f + fragment-ordered bf16 codebook ----------------
__global__ void vq_prep(const float* __restrict__ emb, float* __restrict__ e2f,
                        unsigned short* __restrict__ Bf) {
    int v = blockIdx.x * 256 + threadIdx.x;
    if (v >= VOCAB) return;
    float vals[ED];
    const float4* src = (const float4*)(emb + v * ED);
    double s = 0.0;
    #pragma unroll
    for (int g = 0; g < 16; ++g) {
        float4 f = src[g];
        vals[4*g] = f.x; vals[4*g+1] = f.y; vals[4*g+2] = f.z; vals[4*g+3] = f.w;
        s = fma((double)f.x, (double)f.x, s);
        s = fma((double)f.y, (double)f.y, s);
        s = fma((double)f.z, (double)f.z, s);
        s = fma((double)f.w, (double)f.w, s);
    }
    e2f[v] = (float)s;
    // B-fragment order: lane L = q*16+n holds B[n][k=kh*32+q*8+j], tile = v>>4
    const int tile = v >> 4, n = v & 15;
    #pragma unroll
    for (int k8 = 0; k8 < 8; ++k8) {
        const int kh = k8 >> 2, q = k8 & 3, L = q * 16 + n;
        uint4 pk;
        pk.x = f2bf(vals[k8*8+0]) | (f2bf(vals[k8*8+1]) << 16);
        pk.y = f2bf(vals[k8*8+2]) | (f2bf(vals[k8*8+3]) << 16);
        pk.z = f2bf(vals[k8*8+4]) | (f2bf(vals[k8*8+5]) << 16);
        pk.w = f2bf(vals[k8*8+6]) | (f2bf(vals[k8*8+7]) << 16);
        ((uint4*)Bf)[(tile * 2 + kh) * 64 + L] = pk;
    }
}

// ---------------- filter: barrier-free MFMA scan, top-2 per row --------------
// NOTE: (256,1) — NOT 2/3. Kernel needs ~160 VGPR (measured R5); any tighter
// bound spills to scratch (R6: 850MB spill traffic; R7: partial spill).
__global__ __launch_bounds__(256, 1)
void vq_filter(const float* __restrict__ z, const float* __restrict__ emb,
               const float* __restrict__ e2f, const unsigned short* __restrict__ Bf,
               float* __restrict__ out, double* __restrict__ loss_sum,
               unsigned* __restrict__ hist, unsigned* __restrict__ nflagF,
               unsigned* __restrict__ listF) {
    __shared__ float zs[64 * 67];      // fp32 z rows [row][k], pad 67
    __shared__ uint4 afr[512];         // bf16(-2z) A-fragments [rt][kh][lane]
    __shared__ float Mb1[256], Mb2[256];
    __shared__ int   Mi1[256];
    __shared__ int   final_code[64];

    const int t = threadIdx.x;
    const int w = t >> 6, lane = t & 63;
    const int q = lane >> 4, n_lo = lane & 15;
    const int bk = blockIdx.x;         // 1024 blocks, 64 rows each
    const int n0 = bk * 64;
    const int b  = n0 >> 10;
    const int sbase = n0 & 1023;

    // ---- stage z rows (coalesced 256B per instr) ----
    {
        const int row = t & 63, dg = t >> 6;
        #pragma unroll
        for (int i = 0; i < 16; ++i) {
            int d = dg * 16 + i;
            zs[row * 67 + d] = z[(size_t)b * 65536 + (size_t)d * 1024 + sbase + row];
        }
    }
    __syncthreads();

    // ---- build A-fragments once per block (bf16(-2z), validated numerics) ----
    for (int e = t; e < 512; e += 256) {
        const int rt = e >> 7, kh = (e >> 6) & 1, L = e & 63;
        const int qq = L >> 4, nn = L & 15;
        const int row = rt * 16 + nn, k0 = kh * 32 + qq * 8;
        uint4 pk;
        pk.x = f2bf(-2.0f * zs[row*67 + k0+0]) | (f2bf(-2.0f * zs[row*67 + k0+1]) << 16);
        pk.y = f2bf(-2.0f * zs[row*67 + k0+2]) | (f2bf(-2.0f * zs[row*67 + k0+3]) << 16);
        pk.z = f2bf(-2.0f * zs[row*67 + k0+4]) | (f2bf(-2.0f * zs[row*67 + k0+5]) << 16);
        pk.w = f2bf(-2.0f * zs[row*67 + k0+6]) | (f2bf(-2.0f * zs[row*67 + k0+7]) << 16);
        afr[e] = pk;
    }
    __syncthreads();

    // A-frags to registers (stride-1 b128 LDS reads, conflict-free)
    short8 af[4][2];
    #pragma unroll
    for (int rt = 0; rt < 4; ++rt)
        #pragma unroll
        for (int kh = 0; kh < 2; ++kh)
            af[rt][kh] = ((const short8*)afr)[(rt * 2 + kh) * 64 + lane];

    // per-slot top-2 values + top-1 index. slot -> row = rt*16 + q*4 + reg
    float b1[16], b2[16]; int i1[16];
    #pragma unroll
    for (int sl = 0; sl < 16; ++sl) { b1[sl] = 3.4e38f; b2[sl] = 3.4e38f; i1[sl] = 0; }

    // ---- scan: wave w owns codes [w*256, w*256+256), B-frags from global/L2 ----
    const short8* Bq = (const short8*)Bf + (size_t)(w * 16) * 128;
    #pragma unroll 2
    for (int lt = 0; lt < 16; ++lt) {
        short8 bf0 = Bq[(lt * 2 + 0) * 64 + lane];
        short8 bf1 = Bq[(lt * 2 + 1) * 64 + lane];
        const int codec = w * 256 + lt * 16 + n_lo;
        const float e2c = e2f[codec];
        #pragma unroll
        for (int rt = 0; rt < 4; ++rt) {
            f32x4 a; a[0] = e2c; a[1] = e2c; a[2] = e2c; a[3] = e2c;
            a = __builtin_amdgcn_mfma_f32_16x16x32_bf16(af[rt][0], bf0, a, 0, 0, 0);
            a = __builtin_amdgcn_mfma_f32_16x16x32_bf16(af[rt][1], bf1, a, 0, 0, 0);
            #pragma unroll
            for (int reg = 0; reg < 4; ++reg) {
                const int sl = rt * 4 + reg;
                const float s = a[reg];
                b2[sl] = __builtin_amdgcn_fmed3f(s, b1[sl], b2[sl]);
                const bool lt1 = s < b1[sl];
                i1[sl] = lt1 ? codec : i1[sl];
                b1[sl] = fminf(s, b1[sl]);
            }
        }
    }

    // ---- quad butterfly merge (16 code-lanes): exact top-2 + index ----
    #pragma unroll
    for (int m = 1; m < 16; m <<= 1) {
        #pragma unroll
        for (int sl = 0; sl < 16; ++sl) {
            float ob1 = __shfl_xor(b1[sl], m, 64);
            int   oi1 = __shfl_xor(i1[sl], m, 64);
            float ob2 = __shfl_xor(b2[sl], m, 64);
            float lose = fmaxf(b1[sl], ob1);
            b2[sl] = fminf(fminf(b2[sl], ob2), lose);
            bool take = (ob1 < b1[sl]) || (ob1 == b1[sl] && oi1 < i1[sl]);
            b1[sl] = take ? ob1 : b1[sl];
            i1[sl] = take ? oi1 : i1[sl];
        }
    }
    if (n_lo == 0) {
        #pragma unroll
        for (int rt = 0; rt < 4; ++rt) {
            #pragma unroll
            for (int reg = 0; reg < 4; ++reg) {
                const int row = rt * 16 + q * 4 + reg;
                const int sl = rt * 4 + reg;
                Mb1[w * 64 + row] = b1[sl];
                Mb2[w * 64 + row] = b2[sl];
                Mi1[w * 64 + row] = i1[sl];
            }
        }
    }
    __syncthreads();

    // ---- cross-wave merge + routing (one thread per row) ----
    // Filter commits index/hist for ALL rows; rescue patches diffs only.
    if (t < 64) {
        float B1 = Mb1[t]; int I1 = Mi1[t]; float B2 = Mb2[t];
        #pragma unroll
        for (int ww = 1; ww < 4; ++ww) {
            float v1 = Mb1[ww*64 + t]; int j1 = Mi1[ww*64 + t];
            float v2 = Mb2[ww*64 + t];
            if (v1 < B1 || (v1 == B1 && j1 < I1)) {
                B2 = fminf(B1, v2);
                B1 = v1; I1 = j1;
            } else {
                B2 = fminf(B2, v1);
            }
        }
        const int nrow = n0 + t;
        out[NELEM + nrow] = (float)I1;
        final_code[t] = I1;
        atomicAdd(&hist[I1], 1u);
        if (B2 < B1 + MARGIN) {
            unsigned p = atomicAdd(nflagF, 1u);
            if (p < CAPFULL) listF[p] = (unsigned)nrow;
        }
    }
    __syncthreads();

    // ---- epilogue: coalesced z_q_st + loss for ALL rows ----
    {
        const int row = lane;
        const int code = final_code[row];
        double lsum = 0.0;
        #pragma unroll
        for (int i = 0; i < 16; ++i) {
            const int d = w * 16 + i;
            float zv = zs[row * 67 + d];
            float ee = emb[code * 64 + d];          // divergent gather, L2-hot
            size_t off = (size_t)b * 65536 + (size_t)d * 1024 + sbase + row;
            out[off] = zv + (ee - zv);              // coalesced 256B
            double df = (double)ee - (double)zv;
            lsum = fma(df, df, lsum);
        }
        #pragma unroll
        for (int off = 32; off > 0; off >>= 1)
            lsum += __shfl_down(lsum, off, 64);
        if (lane == 0) atomicAdd(loss_sum, lsum);
    }
}

// ---------------- rescue: exact rescore, patch only changed rows -------------
// Wave w scans code quarter [w*256, w*256+256); all lanes process the SAME
// code at the same time => emb loads are wave-uniform (1 line/instr, L2-hot).
// Thread-per-row (lane = row slot), R2-exact sequential-k fp32 chains.
__global__ __launch_bounds__(256, 1)
void vq_rescue(const float* __restrict__ z, const float* __restrict__ emb,
               const float* __restrict__ e2f, float* __restrict__ out,
               double* __restrict__ loss_sum, unsigned* __restrict__ hist,
               const unsigned* __restrict__ nflagF,
               const unsigned* __restrict__ listF) {
    __shared__ float zs[64 * 66];      // 16.9 KB staged z rows
    __shared__ float Rb[4][64];
    __shared__ int   Ri[4][64];
    __shared__ int   rows_s[64];

    const int t = threadIdx.x, w = t >> 6, lane = t & 63;
    const unsigned nFr = *nflagF;
    const int nF = (int)(nFr < CAPFULL ? nFr : CAPFULL);
    const int base = blockIdx.x * 64;
    if (base >= nF) return;            // block-uniform, before any barrier
    const int mr = (nF - base < 64) ? (nF - base) : 64;

    if (t < 64) rows_s[t] = (t < mr) ? (int)listF[base + t] : 0;
    __syncthreads();

    // stage z rows: thread t -> row slot t&63, d-group t>>6
    {
        const int ri = t & 63, dg = t >> 6;
        if (ri < mr) {
            const int rowid = rows_s[ri];
            const int b = rowid >> 10, s = rowid & 1023;
            #pragma unroll
            for (int i = 0; i < 16; ++i) {
                int d = dg * 16 + i;
                zs[ri * 66 + d] = z[(size_t)b * 65536 + (size_t)d * 1024 + s];
            }
        }
    }
    __syncthreads();

    // per-thread exact scan of this wave's code quarter
    float zr[64];
    float bv = 3.4e38f; int bi = 0x7fffffff;
    {
        const int ri = (lane < mr) ? lane : 0;   // inactive lanes do row 0 (discarded)
        #pragma unroll
        for (int k = 0; k < 64; ++k) zr[k] = zs[ri * 66 + k];
        double a = 0.0;
        #pragma unroll
        for (int k = 0; k < 64; ++k) a = fma((double)zr[k], (double)zr[k], a);
        const float zn = (float)a;               // fl32(fp64 ||z||^2), R2-proven

        #pragma unroll 1
        for (int g = 0; g < 64; ++g) {           // 4 codes per group, ascending
            const int c0 = w * 256 + g * 4;
            const float4* p0 = (const float4*)(emb + (c0 + 0) * 64);
            const float4* p1 = (const float4*)(emb + (c0 + 1) * 64);
            const float4* p2 = (const float4*)(emb + (c0 + 2) * 64);
            const float4* p3 = (const float4*)(emb + (c0 + 3) * 64);
            float m0 = 0.f, m1 = 0.f, m2 = 0.f, m3 = 0.f;
            #pragma unroll
            for (int k4 = 0; k4 < 16; ++k4) {    // R2-exact sequential k
                float4 e0 = p0[k4], e1 = p1[k4], e2_ = p2[k4], e3 = p3[k4];
                m0 = fmaf(zr[4*k4+0], e0.x, m0);  m0 = fmaf(zr[4*k4+1], e0.y, m0);
                m0 = fmaf(zr[4*k4+2], e0.z, m0);  m0 = fmaf(zr[4*k4+3], e0.w, m0);
                m1 = fmaf(zr[4*k4+0], e1.x, m1);  m1 = fmaf(zr[4*k4+1], e1.y, m1);
                m1 = fmaf(zr[4*k4+2], e1.z, m1);  m1 = fmaf(zr[4*k4+3], e1.w, m1);
                m2 = fmaf(zr[4*k4+0], e2_.x, m2); m2 = fmaf(zr[4*k4+1], e2_.y, m2);
                m2 = fmaf(zr[4*k4+2], e2_.z, m2); m2 = fmaf(zr[4*k4+3], e2_.w, m2);
                m3 = fmaf(zr[4*k4+0], e3.x, m3);  m3 = fmaf(zr[4*k4+1], e3.y, m3);
                m3 = fmaf(zr[4*k4+2], e3.z, m3);  m3 = fmaf(zr[4*k4+3], e3.w, m3);
            }
            float tt, d;
            tt = zn + e2f[c0+0]; d = tt - 2.0f*m0; if (d < bv) { bv = d; bi = c0+0; }
            tt = zn + e2f[c0+1]; d = tt - 2.0f*m1; if (d < bv) { bv = d; bi = c0+1; }
            tt = zn + e2f[c0+2]; d = tt - 2.0f*m2; if (d < bv) { bv = d; bi = c0+2; }
            tt = zn + e2f[c0+3]; d = tt - 2.0f*m3; if (d < bv) { bv = d; bi = c0+3; }
        }
    }
    Rb[w][lane] = bv;
    Ri[w][lane] = bi;
    __syncthreads();

    // lexicographic quarter merge (ascending w == ascending code ranges) + patch
    if (t < mr) {
        float BV = Rb[0][t]; int BI = Ri[0][t];
        #pragma unroll
        for (int ww = 1; ww < 4; ++ww) {
            float ov = Rb[ww][t]; int oc = Ri[ww][t];
            if (ov < BV || (ov == BV && oc < BI)) { BV = ov; BI = oc; }
        }
        const int rowid = rows_s[t];
        const int I0 = (int)out[NELEM + rowid];
        if (BI != I0) {                            // patch only real changes
            const int b = rowid >> 10, s = rowid & 1023;
            out[NELEM + rowid] = (float)BI;
            atomicAdd(&hist[BI], 1u);
            atomicAdd(&hist[I0], 0xFFFFFFFFu);     // -1
            double dl = 0.0;
            #pragma unroll 4
            for (int k = 0; k < 64; ++k) {
                float zv = zs[t * 66 + k];
                float en = emb[BI * 64 + k];
                float eo = emb[I0 * 64 + k];
                out[(size_t)b * 65536 + (size_t)k * 1024 + s] = zv + (en - zv);
                double dn = (double)en - (double)zv;
                double dd = (double)eo - (double)zv;
                dl += dn * dn - dd * dd;
            }
            atomicAdd(loss_sum, dl);
        }
    }
}

// ---------------- finalize ----------------
__global__ void vq_finalize_kernel(const unsigned* __restrict__ hist,
                                   const double* __restrict__ loss_sum,
                                   float* __restrict__ out) {
    __shared__ double red[256];
    int t = threadIdx.x;
    double ssum = 0.0;
    for (int i = t; i < VOCAB; i += 256) {
        double p = (double)hist[i] / (double)NROWS;
        ssum += p * log(p + 1e-10);
    }
    red[t] = ssum;
    __syncthreads();
    for (int off = 128; off > 0; off >>= 1) {
        if (t < off) red[t] += red[t + off];
        __syncthreads();
    }
    if (t == 0) {
        double qv = loss_sum[0] / (double)NELEM;
        out[NELEM + NROWS + 0] = (float)qv;
        out[NELEM + NROWS + 1] = (float)(qv * 0.25);
        out[NELEM + NROWS + 2] = (float)exp(-red[0]);
    }
}

extern "C" void kernel_launch(void* const* d_in, const int* in_sizes, int n_in,
                              void* d_out, int out_size, void* d_ws, size_t ws_size,
                              hipStream_t stream) {
    const float* z   = (const float*)d_in[0];   // (64,64,32,32) fp32
    const float* emb = (const float*)d_in[1];   // (1024,64) fp32
    float* out = (float*)d_out;

    float*          e2f   = (float*)d_ws;
    unsigned short* Bf    = (unsigned short*)((char*)d_ws + 4096);
    double*         loss  = (double*)((char*)d_ws + 135168);
    unsigned*       nflF  = (unsigned*)((char*)d_ws + 135176);
    unsigned*       hist  = (unsigned*)((char*)d_ws + 135184);
    unsigned*       listF = (unsigned*)((char*)d_ws + 139280);

    // zero loss + nflagF + pad + hist
    hipMemsetAsync((char*)d_ws + 135168, 0, 4112, stream);

    vq_prep<<<dim3(4), dim3(256), 0, stream>>>(emb, e2f, Bf);
    vq_filter<<<dim3(1024), dim3(256), 0, stream>>>(z, emb, e2f, Bf, out, loss,
                                                    hist, nflF, listF);
    vq_rescue<<<dim3(1024), dim3(256), 0, stream>>>(z, emb, e2f, out, loss, hist,
                                                    nflF, listF);
    vq_finalize_kernel<<<dim3(1), dim3(256), 0, stream>>>(hist, loss, out);
}

// Round 9
// 249.986 us; speedup vs baseline: 2.1659x; 1.3332x over previous
//
#include <hip/hip_runtime.h>
#include <math.h>

#define VOCAB 1024
#define ED 64
#define NROWS 65536            // 64*32*32 flattened rows
#define NELEM 4194304          // 64*64*32*32
#define MARGIN 2.0e-4f         // validated R3/R4/R5/R7/R8 (passed, absmax 0)
#define CAPFULL 65536          // = NROWS, cannot overflow
#define CAPC 16384             // cand slots (aliases Bf; nF~2700 measured R8)

typedef __attribute__((ext_vector_type(8))) short short8;
typedef __attribute__((ext_vector_type(4))) float f32x4;

__device__ __forceinline__ unsigned f2bf(float f) {
    unsigned u = __float_as_uint(f);
    u += 0x7fff + ((u >> 16) & 1);   // RNE to bf16
    return u >> 16;
}

// monotone total-order key for float (handles negatives; d>0 in practice)
__device__ __forceinline__ unsigned fkey(float f) {
    unsigned b = __float_as_uint(f);
    return b ^ ((b >> 31) ? 0xFFFFFFFFu : 0x80000000u);
}

// ws layout:
//   [0,      4096)   float  e2f[1024]        fl32(fp64 ||e||^2)  (R2-proven)
//   [4096,   135168) ushort Bf[...]          bf16 codebook (filter only)
//                    -- after filter: u64 cand[CAPC] aliases this region --
//   [135168, 135176) double loss_sum
//   [135176, 135180) unsigned nflagF
//   [135180, 135184) pad
//   [135184, 139280) unsigned hist[1024]
//   [139280, 401424) unsigned listF[CAPFULL]

// ---------------- prep: e2f + fragment-ordered bf16 codebook ----------------
__global__ void vq_prep(const float* __restrict__ emb, float* __restrict__ e2f,
                        unsigned short* __restrict__ Bf) {
    int v = blockIdx.x * 256 + threadIdx.x;
    if (v >= VOCAB) return;
    float vals[ED];
    const float4* src = (const float4*)(emb + v * ED);
    double s = 0.0;
    #pragma unroll
    for (int g = 0; g < 16; ++g) {
        float4 f = src[g];
        vals[4*g] = f.x; vals[4*g+1] = f.y; vals[4*g+2] = f.z; vals[4*g+3] = f.w;
        s = fma((double)f.x, (double)f.x, s);
        s = fma((double)f.y, (double)f.y, s);
        s = fma((double)f.z, (double)f.z, s);
        s = fma((double)f.w, (double)f.w, s);
    }
    e2f[v] = (float)s;
    const int tile = v >> 4, n = v & 15;
    #pragma unroll
    for (int k8 = 0; k8 < 8; ++k8) {
        const int kh = k8 >> 2, q = k8 & 3, L = q * 16 + n;
        uint4 pk;
        pk.x = f2bf(vals[k8*8+0]) | (f2bf(vals[k8*8+1]) << 16);
        pk.y = f2bf(vals[k8*8+2]) | (f2bf(vals[k8*8+3]) << 16);
        pk.z = f2bf(vals[k8*8+4]) | (f2bf(vals[k8*8+5]) << 16);
        pk.w = f2bf(vals[k8*8+6]) | (f2bf(vals[k8*8+7]) << 16);
        ((uint4*)Bf)[(tile * 2 + kh) * 64 + L] = pk;
    }
}

// ---------------- filter: identical to R8 (passed, absmax 0) ----------------
__global__ __launch_bounds__(256, 1)
void vq_filter(const float* __restrict__ z, const float* __restrict__ emb,
               const float* __restrict__ e2f, const unsigned short* __restrict__ Bf,
               float* __restrict__ out, double* __restrict__ loss_sum,
               unsigned* __restrict__ hist, unsigned* __restrict__ nflagF,
               unsigned* __restrict__ listF) {
    __shared__ float zs[64 * 67];
    __shared__ uint4 afr[512];
    __shared__ float Mb1[256], Mb2[256];
    __shared__ int   Mi1[256];
    __shared__ int   final_code[64];

    const int t = threadIdx.x;
    const int w = t >> 6, lane = t & 63;
    const int q = lane >> 4, n_lo = lane & 15;
    const int bk = blockIdx.x;
    const int n0 = bk * 64;
    const int b  = n0 >> 10;
    const int sbase = n0 & 1023;

    {
        const int row = t & 63, dg = t >> 6;
        #pragma unroll
        for (int i = 0; i < 16; ++i) {
            int d = dg * 16 + i;
            zs[row * 67 + d] = z[(size_t)b * 65536 + (size_t)d * 1024 + sbase + row];
        }
    }
    __syncthreads();

    for (int e = t; e < 512; e += 256) {
        const int rt = e >> 7, kh = (e >> 6) & 1, L = e & 63;
        const int qq = L >> 4, nn = L & 15;
        const int row = rt * 16 + nn, k0 = kh * 32 + qq * 8;
        uint4 pk;
        pk.x = f2bf(-2.0f * zs[row*67 + k0+0]) | (f2bf(-2.0f * zs[row*67 + k0+1]) << 16);
        pk.y = f2bf(-2.0f * zs[row*67 + k0+2]) | (f2bf(-2.0f * zs[row*67 + k0+3]) << 16);
        pk.z = f2bf(-2.0f * zs[row*67 + k0+4]) | (f2bf(-2.0f * zs[row*67 + k0+5]) << 16);
        pk.w = f2bf(-2.0f * zs[row*67 + k0+6]) | (f2bf(-2.0f * zs[row*67 + k0+7]) << 16);
        afr[e] = pk;
    }
    __syncthreads();

    short8 af[4][2];
    #pragma unroll
    for (int rt = 0; rt < 4; ++rt)
        #pragma unroll
        for (int kh = 0; kh < 2; ++kh)
            af[rt][kh] = ((const short8*)afr)[(rt * 2 + kh) * 64 + lane];

    float b1[16], b2[16]; int i1[16];
    #pragma unroll
    for (int sl = 0; sl < 16; ++sl) { b1[sl] = 3.4e38f; b2[sl] = 3.4e38f; i1[sl] = 0; }

    const short8* Bq = (const short8*)Bf + (size_t)(w * 16) * 128;
    #pragma unroll 2
    for (int lt = 0; lt < 16; ++lt) {
        short8 bf0 = Bq[(lt * 2 + 0) * 64 + lane];
        short8 bf1 = Bq[(lt * 2 + 1) * 64 + lane];
        const int codec = w * 256 + lt * 16 + n_lo;
        const float e2c = e2f[codec];
        #pragma unroll
        for (int rt = 0; rt < 4; ++rt) {
            f32x4 a; a[0] = e2c; a[1] = e2c; a[2] = e2c; a[3] = e2c;
            a = __builtin_amdgcn_mfma_f32_16x16x32_bf16(af[rt][0], bf0, a, 0, 0, 0);
            a = __builtin_amdgcn_mfma_f32_16x16x32_bf16(af[rt][1], bf1, a, 0, 0, 0);
            #pragma unroll
            for (int reg = 0; reg < 4; ++reg) {
                const int sl = rt * 4 + reg;
                const float s = a[reg];
                b2[sl] = __builtin_amdgcn_fmed3f(s, b1[sl], b2[sl]);
                const bool lt1 = s < b1[sl];
                i1[sl] = lt1 ? codec : i1[sl];
                b1[sl] = fminf(s, b1[sl]);
            }
        }
    }

    #pragma unroll
    for (int m = 1; m < 16; m <<= 1) {
        #pragma unroll
        for (int sl = 0; sl < 16; ++sl) {
            float ob1 = __shfl_xor(b1[sl], m, 64);
            int   oi1 = __shfl_xor(i1[sl], m, 64);
            float ob2 = __shfl_xor(b2[sl], m, 64);
            float lose = fmaxf(b1[sl], ob1);
            b2[sl] = fminf(fminf(b2[sl], ob2), lose);
            bool take = (ob1 < b1[sl]) || (ob1 == b1[sl] && oi1 < i1[sl]);
            b1[sl] = take ? ob1 : b1[sl];
            i1[sl] = take ? oi1 : i1[sl];
        }
    }
    if (n_lo == 0) {
        #pragma unroll
        for (int rt = 0; rt < 4; ++rt) {
            #pragma unroll
            for (int reg = 0; reg < 4; ++reg) {
                const int row = rt * 16 + q * 4 + reg;
                const int sl = rt * 4 + reg;
                Mb1[w * 64 + row] = b1[sl];
                Mb2[w * 64 + row] = b2[sl];
                Mi1[w * 64 + row] = i1[sl];
            }
        }
    }
    __syncthreads();

    if (t < 64) {
        float B1 = Mb1[t]; int I1 = Mi1[t]; float B2 = Mb2[t];
        #pragma unroll
        for (int ww = 1; ww < 4; ++ww) {
            float v1 = Mb1[ww*64 + t]; int j1 = Mi1[ww*64 + t];
            float v2 = Mb2[ww*64 + t];
            if (v1 < B1 || (v1 == B1 && j1 < I1)) {
                B2 = fminf(B1, v2);
                B1 = v1; I1 = j1;
            } else {
                B2 = fminf(B2, v1);
            }
        }
        const int nrow = n0 + t;
        out[NELEM + nrow] = (float)I1;
        final_code[t] = I1;
        atomicAdd(&hist[I1], 1u);
        if (B2 < B1 + MARGIN) {
            unsigned p = atomicAdd(nflagF, 1u);
            if (p < CAPFULL) listF[p] = (unsigned)nrow;
        }
    }
    __syncthreads();

    {
        const int row = lane;
        const int code = final_code[row];
        double lsum = 0.0;
        #pragma unroll
        for (int i = 0; i < 16; ++i) {
            const int d = w * 16 + i;
            float zv = zs[row * 67 + d];
            float ee = emb[code * 64 + d];
            size_t off = (size_t)b * 65536 + (size_t)d * 1024 + sbase + row;
            out[off] = zv + (ee - zv);
            double df = (double)ee - (double)zv;
            lsum = fma(df, df, lsum);
        }
        #pragma unroll
        for (int off = 32; off > 0; off >>= 1)
            lsum += __shfl_down(lsum, off, 64);
        if (lane == 0) atomicAdd(loss_sum, lsum);
    }
}

// ---------------- rescue: exact rescore -> atomicMin(u64) per flagged row ----
// block = (rowchunk = bid>>3: 64 rows, codechunk = bid&7: 128 codes).
// Wave w scans 32 codes; lane = row slot; emb via wave-uniform GLOBAL float4
// (VMEM pipe, L2-hot); z rows in LDS pad-65 (2-way banks, free).
__global__ __launch_bounds__(256)
void vq_rescue(const float* __restrict__ z, const float* __restrict__ emb,
               const float* __restrict__ e2f,
               unsigned long long* __restrict__ cand,
               const unsigned* __restrict__ nflagF,
               const unsigned* __restrict__ listF) {
    __shared__ float zs[64 * 65];
    __shared__ float znl[64];
    __shared__ unsigned long long mrg[4][64];

    const int t = threadIdx.x, w = t >> 6, lane = t & 63;
    const unsigned nFr = *nflagF;
    const int nF = (int)(nFr < CAPC ? nFr : CAPC);
    const int base = (blockIdx.x >> 3) * 64;
    const int cc = blockIdx.x & 7;
    if (base >= nF) return;            // block-uniform, before any barrier
    const int mr = (nF - base < 64) ? (nF - base) : 64;

    // stage z rows (thread -> row slot t&63, d-group t>>6)
    {
        const int ri = t & 63, dg = t >> 6;
        if (ri < mr) {
            const int rowid = (int)listF[base + ri];
            const int b = rowid >> 10, s = rowid & 1023;
            #pragma unroll
            for (int i = 0; i < 16; ++i) {
                int d = dg * 16 + i;
                zs[ri * 65 + d] = z[(size_t)b * 65536 + (size_t)d * 1024 + s];
            }
        }
    }
    __syncthreads();
    if (t < 64) {
        double a = 0.0;
        #pragma unroll
        for (int k = 0; k < 64; ++k) {
            double x = (double)zs[t * 65 + k];
            a = fma(x, x, a);
        }
        znl[t] = (float)a;             // fl32(fp64 ||z||^2), R2-proven
    }
    __syncthreads();

    const int ri = (lane < mr) ? lane : 0;
    const float zn = znl[ri];
    const float* zrow = &zs[ri * 65];

    float bv = 3.4e38f; int bi = 0x7fffffff;
    const int cbase = cc * 128 + w * 32;
    #pragma unroll 1
    for (int p = 0; p < 16; ++p) {                 // 2 codes per iter, ascending
        const int c0 = cbase + p * 2;
        const float4* p0 = (const float4*)(emb + (c0 + 0) * 64);   // wave-uniform
        const float4* p1 = (const float4*)(emb + (c0 + 1) * 64);
        float m0 = 0.f, m1 = 0.f;
        #pragma unroll
        for (int k4 = 0; k4 < 16; ++k4) {          // R2-exact sequential k
            float4 zq = *(const float4*)&zrow[k4 * 4];
            float4 e0 = p0[k4], e1 = p1[k4];
            m0 = fmaf(zq.x, e0.x, m0); m0 = fmaf(zq.y, e0.y, m0);
            m0 = fmaf(zq.z, e0.z, m0); m0 = fmaf(zq.w, e0.w, m0);
            m1 = fmaf(zq.x, e1.x, m1); m1 = fmaf(zq.y, e1.y, m1);
            m1 = fmaf(zq.z, e1.z, m1); m1 = fmaf(zq.w, e1.w, m1);
        }
        float tt0 = zn + e2f[c0];     float d0 = tt0 - 2.0f * m0;
        float tt1 = zn + e2f[c0 + 1]; float d1 = tt1 - 2.0f * m1;
        if (d0 < bv) { bv = d0; bi = c0; }
        if (d1 < bv) { bv = d1; bi = c0 + 1; }
    }
    mrg[w][lane] = ((unsigned long long)fkey(bv) << 32) | (unsigned)bi;
    __syncthreads();

    if (t < mr) {
        unsigned long long m = mrg[0][t];
        #pragma unroll
        for (int ww = 1; ww < 4; ++ww) {
            unsigned long long o = mrg[ww][t];
            m = (o < m) ? o : m;
        }
        atomicMin(&cand[base + t], m);
    }
}

// ---------------- patch: apply exact winner where it differs -----------------
__global__ __launch_bounds__(256)
void vq_patch(const float* __restrict__ z, const float* __restrict__ emb,
              const float* __restrict__ e2f, float* __restrict__ out,
              double* __restrict__ loss_sum, unsigned* __restrict__ hist,
              const unsigned* __restrict__ nflagF,
              const unsigned* __restrict__ listF,
              const unsigned long long* __restrict__ cand) {
    const int fi = blockIdx.x * 256 + threadIdx.x;
    const unsigned nFr = *nflagF;
    const int nF = (int)(nFr < CAPFULL ? nFr : CAPFULL);
    if (fi >= nF) return;
    const int rowid = (int)listF[fi];
    const int b = rowid >> 10, s = rowid & 1023;

    int BI;
    if (fi < CAPC) {
        BI = (int)(cand[fi] & 0xFFFFFFFFull);
    } else {
        // unreachable fallback (nF > 16384 is >250 sigma): serial exact scan
        float zr[64];
        #pragma unroll
        for (int k = 0; k < 64; ++k)
            zr[k] = z[(size_t)b * 65536 + (size_t)k * 1024 + s];
        double a = 0.0;
        #pragma unroll
        for (int k = 0; k < 64; ++k) a = fma((double)zr[k], (double)zr[k], a);
        const float zn = (float)a;
        float bv = 3.4e38f; BI = 0;
        for (int c = 0; c < VOCAB; ++c) {
            float m = 0.f;
            const float4* ep = (const float4*)(emb + c * 64);
            #pragma unroll
            for (int k4 = 0; k4 < 16; ++k4) {
                float4 e4 = ep[k4];
                m = fmaf(zr[4*k4+0], e4.x, m); m = fmaf(zr[4*k4+1], e4.y, m);
                m = fmaf(zr[4*k4+2], e4.z, m); m = fmaf(zr[4*k4+3], e4.w, m);
            }
            float tt = zn + e2f[c];
            float d = tt - 2.0f * m;
            if (d < bv) { bv = d; BI = c; }
        }
    }

    const int I0 = (int)out[NELEM + rowid];
    if (BI != I0) {
        out[NELEM + rowid] = (float)BI;
        atomicAdd(&hist[BI], 1u);
        atomicAdd(&hist[I0], 0xFFFFFFFFu);         // -1
        double dl = 0.0;
        #pragma unroll 4
        for (int k = 0; k < 64; ++k) {
            float zv = z[(size_t)b * 65536 + (size_t)k * 1024 + s];
            float en = emb[BI * 64 + k];
            float eo = emb[I0 * 64 + k];
            out[(size_t)b * 65536 + (size_t)k * 1024 + s] = zv + (en - zv);
            double dn = (double)en - (double)zv;
            double dd = (double)eo - (double)zv;
            dl += dn * dn - dd * dd;
        }
        atomicAdd(loss_sum, dl);
    }
}

// ---------------- finalize ----------------
__global__ void vq_finalize_kernel(const unsigned* __restrict__ hist,
                                   const double* __restrict__ loss_sum,
                                   float* __restrict__ out) {
    __shared__ double red[256];
    int t = threadIdx.x;
    double ssum = 0.0;
    for (int i = t; i < VOCAB; i += 256) {
        double p = (double)hist[i] / (double)NROWS;
        ssum += p * log(p + 1e-10);
    }
    red[t] = ssum;
    __syncthreads();
    for (int off = 128; off > 0; off >>= 1) {
        if (t < off) red[t] += red[t + off];
        __syncthreads();
    }
    if (t == 0) {
        double qv = loss_sum[0] / (double)NELEM;
        out[NELEM + NROWS + 0] = (float)qv;
        out[NELEM + NROWS + 1] = (float)(qv * 0.25);
        out[NELEM + NROWS + 2] = (float)exp(-red[0]);
    }
}

extern "C" void kernel_launch(void* const* d_in, const int* in_sizes, int n_in,
                              void* d_out, int out_size, void* d_ws, size_t ws_size,
                              hipStream_t stream) {
    const float* z   = (const float*)d_in[0];   // (64,64,32,32) fp32
    const float* emb = (const float*)d_in[1];   // (1024,64) fp32
    float* out = (float*)d_out;

    float*              e2f   = (float*)d_ws;
    unsigned short*     Bf    = (unsigned short*)((char*)d_ws + 4096);
    unsigned long long* cand  = (unsigned long long*)((char*)d_ws + 4096); // aliases Bf
    double*             loss  = (double*)((char*)d_ws + 135168);
    unsigned*           nflF  = (unsigned*)((char*)d_ws + 135176);
    unsigned*           hist  = (unsigned*)((char*)d_ws + 135184);
    unsigned*           listF = (unsigned*)((char*)d_ws + 139280);

    // zero loss + nflagF + pad + hist
    hipMemsetAsync((char*)d_ws + 135168, 0, 4112, stream);

    vq_prep<<<dim3(4), dim3(256), 0, stream>>>(emb, e2f, Bf);
    vq_filter<<<dim3(1024), dim3(256), 0, stream>>>(z, emb, e2f, Bf, out, loss,
                                                    hist, nflF, listF);
    // Bf is dead now; init cand = 0xFF.. (stream-ordered after filter)
    hipMemsetAsync((char*)d_ws + 4096, 0xFF, CAPC * 8, stream);
    vq_rescue<<<dim3(2048), dim3(256), 0, stream>>>(z, emb, e2f, cand, nflF, listF);
    vq_patch<<<dim3(CAPFULL / 256), dim3(256), 0, stream>>>(z, emb, e2f, out,
                                                            loss, hist, nflF,
                                                            listF, cand);
    vq_finalize_kernel<<<dim3(1), dim3(256), 0, stream>>>(hist, loss, out);
}